// Round 10
// baseline (739.713 us; speedup 1.0000x reference)
//
#include <hip/hip_runtime.h>
#include <hip/hip_bf16.h>
#include <math.h>

typedef __bf16 bf16;
typedef bf16 bf16x8 __attribute__((ext_vector_type(8)));
typedef bf16 bf16x4 __attribute__((ext_vector_type(4)));
typedef float f32x4 __attribute__((ext_vector_type(4)));

#define MFMA16(A,B,C) __builtin_amdgcn_mfma_f32_16x16x32_bf16(A,B,C,0,0,0)

static constexpr int QKV_ELEMS  = 768 * 256;
static constexpr int PROJ_ELEMS = 256 * 256;
// per (b,w): 8 heads x {q[64][32], k[64][32], vT[32][64]} bf16 = 6144 elems/head
static constexpr size_t QKVWS_ELEMS = (size_t)4096 * 8 * 6144;

static __device__ __forceinline__ void lds_fence() {
    asm volatile("s_waitcnt lgkmcnt(0)" ::: "memory");
    __builtin_amdgcn_sched_barrier(0);
}

static __device__ __forceinline__ unsigned pack2(float a, float b) {
    bf16 xa = (bf16)a, xb = (bf16)b;
    unsigned short ua, ub;
    __builtin_memcpy(&ua, &xa, 2);
    __builtin_memcpy(&ub, &xb, 2);
    return (unsigned)ua | ((unsigned)ub << 16);
}

// Build an MFMA A/B fragment (bf16x8) from packed C-fragment registers.
#define BUILD_FRAG(dst, PKL0, PKL1, PKH0, PKH1)                               \
  {                                                                            \
    int sA = ((lane & 16) << 1) + lo;                                          \
    int sB = sA + 16;                                                          \
    int a0 = __shfl((int)(PKL0), sA), a1 = __shfl((int)(PKL1), sA);            \
    int a2 = __shfl((int)(PKL0), sB), a3 = __shfl((int)(PKL1), sB);            \
    int b0 = __shfl((int)(PKH0), sA), b1 = __shfl((int)(PKH1), sA);            \
    int b2 = __shfl((int)(PKH0), sB), b3 = __shfl((int)(PKH1), sB);            \
    union { int w[4]; bf16x8 v; } u_;                                          \
    bool uh_ = (lane >= 32);                                                   \
    u_.w[0] = uh_ ? b0 : a0; u_.w[1] = uh_ ? b1 : a1;                          \
    u_.w[2] = uh_ ? b2 : a2; u_.w[3] = uh_ ? b3 : a3;                          \
    dst = u_.v;                                                                \
  }

// ---- K0: cast weights fp32 -> bf16 into ws ----
__global__ void cvt_weights(const float* __restrict__ qkv_w,
                            const float* __restrict__ proj_w,
                            bf16* __restrict__ wq, bf16* __restrict__ wp) {
    int i = blockIdx.x * 256 + threadIdx.x;
    if (i < QKV_ELEMS) wq[i] = (bf16)qkv_w[i];
    int j = i - QKV_ELEMS;
    if (j >= 0 && j < PROJ_ELEMS) wp[j] = (bf16)proj_w[j];
}

// ======================= K1: shift + QKV GEMM -> ws =======================
// 256 thr = 4 waves; wave w owns heads 2w,2w+1. NO x staging: B-fragments are
// lane-contiguous 32B of one x row -> loaded directly from global (L2-hot on
// re-reads) via 4 per-lane row pointers + immediate offsets. Weight frags in
// half-pass groups af[4][4] (64 regs) so the compiler can genuinely hoist.
__global__ __launch_bounds__(256, 2)
void swin_qkv(const float* __restrict__ x,
              const bf16* __restrict__ wqkv,
              bf16* __restrict__ qkv_ws)
{
    __shared__ alignas(16) unsigned char vtbuf[4][4096];    // per-wave vT staging

    const int tid  = threadIdx.x;
    const int wave = tid >> 6, lane = tid & 63;
    const int hi   = lane >> 4, lo = lane & 15;
    const int b    = blockIdx.x >> 6;
    const int w    = blockIdx.x & 63;
    const int wh   = w >> 3, wwi = w & 7;
    const f32x4 zero4 = {0.f, 0.f, 0.f, 0.f};

    // per-lane shifted row pointers for the 4 Nt token groups
    const float* xrow[4];
    #pragma unroll
    for (int Nt = 0; Nt < 4; ++Nt) {
        int tok = Nt * 16 + lo;
        int gy = ((wh << 3) + (tok >> 3) + 4) & 63;
        int gx = ((wwi << 3) + (tok & 7) + 4) & 63;
        xrow[Nt] = x + (((b << 6) + gy) * 64 + gx) * 256;
    }

    bf16* base0 = qkv_ws + ((size_t)blockIdx.x * 8 + 2 * wave) * 6144;

    #pragma unroll
    for (int pass = 0; pass < 3; ++pass) {           // 0=Q, 1=K, 2=V
        const int secb = pass * 256 + 64 * wave;     // 64 contiguous weight rows

        f32x4 acc[4][4];
        #pragma unroll
        for (int Mt = 0; Mt < 4; ++Mt)
            #pragma unroll
            for (int Nt = 0; Nt < 4; ++Nt) acc[Mt][Nt] = zero4;

        #pragma unroll
        for (int half = 0; half < 2; ++half) {
            // half-pass weight fragment group (64 regs -> hoistable)
            bf16x8 af[4][4];
            #pragma unroll
            for (int k4 = 0; k4 < 4; ++k4)
                #pragma unroll
                for (int Mt = 0; Mt < 4; ++Mt)
                    af[k4][Mt] = *(const bf16x8*)(wqkv + (secb + 16 * Mt + lo) * 256
                                                  + (half * 4 + k4) * 32 + hi * 8);
            #pragma unroll
            for (int k4 = 0; k4 < 4; ++k4) {
                const int kk = half * 4 + k4;
                bf16x8 bx[4];
                #pragma unroll
                for (int Nt = 0; Nt < 4; ++Nt) {
                    const float4 a = *(const float4*)(xrow[Nt] + kk * 32 + hi * 8);
                    const float4 c = *(const float4*)(xrow[Nt] + kk * 32 + hi * 8 + 4);
                    union { unsigned u[4]; bf16x8 v; } r;
                    r.u[0] = pack2(a.x, a.y); r.u[1] = pack2(a.z, a.w);
                    r.u[2] = pack2(c.x, c.y); r.u[3] = pack2(c.z, c.w);
                    bx[Nt] = r.v;
                }
                #pragma unroll
                for (int Mt = 0; Mt < 4; ++Mt)
                    #pragma unroll
                    for (int Nt = 0; Nt < 4; ++Nt)
                        acc[Mt][Nt] = MFMA16(af[k4][Mt], bx[Nt], acc[Mt][Nt]);
            }
        }

        if (pass < 2) {
            // q/k as [tok][32] per head; head = 2w + (Mt>>1), d = 16*(Mt&1)+4*hi+r
            #pragma unroll
            for (int Mt = 0; Mt < 4; ++Mt) {
                bf16* hb = base0 + (Mt >> 1) * 6144 + pass * 2048;
                int d0 = ((Mt & 1) << 4) + 4 * hi;
                #pragma unroll
                for (int Nt = 0; Nt < 4; ++Nt) {
                    int tok = Nt * 16 + lo;
                    bf16x4 v;
                    #pragma unroll
                    for (int r = 0; r < 4; ++r) v[r] = (bf16)acc[Mt][Nt][r];
                    *(bf16x4*)(hb + tok * 32 + d0) = v;
                }
            }
        } else {
            // vT per head: scalar ds_writes (swizzled) -> b128 read-back -> b128 global
            unsigned char* vt = vtbuf[wave];
            #pragma unroll
            for (int hh = 0; hh < 2; ++hh) {
                #pragma unroll
                for (int m = 0; m < 2; ++m) {
                    int Mt = 2 * hh + m;
                    #pragma unroll
                    for (int Nt = 0; Nt < 4; ++Nt) {
                        int tok = Nt * 16 + lo;
                        #pragma unroll
                        for (int r = 0; r < 4; ++r) {
                            int d = (m << 4) + 4 * hi + r;         // (d>>2)&3 == hi
                            int byte = d * 128 + ((2 * tok) ^ (hi << 5));
                            *(bf16*)(vt + byte) = (bf16)acc[Mt][Nt][r];
                        }
                    }
                }
                lds_fence();   // writes visible before read-back
                bf16* hb = base0 + hh * 6144 + 4096;
                #pragma unroll
                for (int i = 0; i < 4; ++i) {
                    int d    = lane >> 1;
                    int tok0 = ((lane & 1) << 3) + (i << 4);
                    int byte = d * 128 + ((2 * tok0) ^ (((d >> 2) & 3) << 5));
                    bf16x8 vv = *(const bf16x8*)(vt + byte);
                    *(bf16x8*)(hb + d * 64 + tok0) = vv;
                }
                lds_fence();   // reads complete before next head overwrites vt
            }
        }
    }
}

// =================== K2: attention + proj + unshift ===================
// 256 thr = 4 waves; wave w does heads 2w,2w+1. All attention fragments of
// BOTH heads batch-prefetched (24 x 16B) before any compute; proj weights
// batched as bB[8][4].
__global__ __launch_bounds__(256, 2)
void swin_attn_proj(const bf16* __restrict__ qkv_ws,
                    const bf16* __restrict__ wproj,
                    const float* __restrict__ proj_b,
                    const float* __restrict__ pose_g,
                    float* __restrict__ out)
{
    __shared__ alignas(16) unsigned char xbuf[64 * 512];   // attn-out [64 tok][256 ch]
    __shared__ float pose[225];

    const int tid  = threadIdx.x;
    const int wave = tid >> 6, lane = tid & 63;
    const int hi   = lane >> 4, lo = lane & 15;
    const int b    = blockIdx.x >> 6;
    const int w    = blockIdx.x & 63;
    const int wh   = w >> 3, wwi = w & 7;
    const bool mlow = (wh == 7), mright = (wwi == 7);
    const f32x4 zero4 = {0.f, 0.f, 0.f, 0.f};

    if (tid < 225) pose[tid] = pose_g[tid];
    __syncthreads();

    const bool colmask_ = mright && (((lo & 7) >= 4) != (hi & 1));

    // fr[hp][0..3]=kA, [4..7]=qB, [8..11]=va (va[ks*2+dMt])
    bf16x8 fr[2][12];
    {
        const bf16* b0 = qkv_ws + ((size_t)blockIdx.x * 8 + 2 * wave) * 6144;
        #pragma unroll
        for (int hp = 0; hp < 2; ++hp) {
            const bf16* bb = b0 + hp * 6144;
            #pragma unroll
            for (int i = 0; i < 4; ++i) {
                fr[hp][i]     = *(const bf16x8*)(bb + 2048 + (16 * i + lo) * 32 + hi * 8);
                fr[hp][4 + i] = *(const bf16x8*)(bb + (16 * i + lo) * 32 + hi * 8);
                fr[hp][8 + i] = *(const bf16x8*)(bb + 4096 + (16 * (i & 1) + lo) * 64 + (i >> 1) * 32 + hi * 8);
            }
        }
    }

    #pragma unroll
    for (int hp = 0; hp < 2; ++hp) {
        const int h = 2 * wave + hp;

        #pragma unroll
        for (int it = 0; it < 4; ++it) {
            f32x4 s4[4];
            #pragma unroll
            for (int jt = 0; jt < 4; ++jt) s4[jt] = MFMA16(fr[hp][jt], fr[hp][4 + it], zero4);

            float mx = -INFINITY;
            #pragma unroll
            for (int jt = 0; jt < 4; ++jt) {
                bool tilemask = mlow && ((it >= 2) != (jt >= 2));
                #pragma unroll
                for (int r = 0; r < 4; ++r) {
                    int drow = 2 * jt + (hi >> 1) - 2 * it - (lo >> 3) + 7;
                    int dcol = 4 * (hi & 1) + r - (lo & 7) + 7;
                    float s = s4[jt][r] * 0.17677669529663687f + pose[drow * 15 + dcol];
                    if (tilemask | colmask_) s = -INFINITY;
                    s4[jt][r] = s;
                    mx = fmaxf(mx, s);
                }
            }
            mx = fmaxf(mx, __shfl_xor(mx, 16));
            mx = fmaxf(mx, __shfl_xor(mx, 32));
            float sum = 0.f;
            #pragma unroll
            for (int jt = 0; jt < 4; ++jt)
                #pragma unroll
                for (int r = 0; r < 4; ++r) {
                    float e = __expf(s4[jt][r] - mx);
                    s4[jt][r] = e; sum += e;
                }
            sum += __shfl_xor(sum, 16);
            sum += __shfl_xor(sum, 32);
            float riv = 1.0f / sum;

            unsigned pk[4][2];
            #pragma unroll
            for (int jt = 0; jt < 4; ++jt)
                #pragma unroll
                for (int p = 0; p < 2; ++p)
                    pk[jt][p] = pack2(s4[jt][2 * p], s4[jt][2 * p + 1]);

            f32x4 o2[2] = {zero4, zero4};
            #pragma unroll
            for (int ks = 0; ks < 2; ++ks) {
                bf16x8 pB;
                BUILD_FRAG(pB, pk[2 * ks][0], pk[2 * ks][1], pk[2 * ks + 1][0], pk[2 * ks + 1][1]);
                #pragma unroll
                for (int dMt = 0; dMt < 2; ++dMt)
                    o2[dMt] = MFMA16(fr[hp][8 + ks * 2 + dMt], pB, o2[dMt]);
            }
            #pragma unroll
            for (int dMt = 0; dMt < 2; ++dMt) {
                int tok = it * 16 + lo;
                bf16x4 v;
                #pragma unroll
                for (int r = 0; r < 4; ++r) v[r] = (bf16)(o2[dMt][r] * riv);
                int chunk = ((h << 2) + (dMt << 1) + (hi >> 1)) ^ (tok & 7);
                *(bf16x4*)(xbuf + tok * 512 + (chunk << 4) + ((hi & 1) << 3)) = v;
            }
        }
    }
    __syncthreads();

    // ===== proj: out = ao * Wp^T + bias; wave w does out-ch 64w..64w+63 =====
    bf16x8 bB[8][4];
    #pragma unroll
    for (int kk = 0; kk < 8; ++kk)
        #pragma unroll
        for (int nt = 0; nt < 4; ++nt) {
            int c = wave * 64 + nt * 16 + lo;
            bB[kk][nt] = *(const bf16x8*)(wproj + c * 256 + kk * 32 + hi * 8);
        }

    f32x4 pacc[4][4];
    #pragma unroll
    for (int Mt = 0; Mt < 4; ++Mt)
        #pragma unroll
        for (int nt = 0; nt < 4; ++nt) pacc[Mt][nt] = zero4;
    #pragma unroll
    for (int kk = 0; kk < 8; ++kk) {
        bf16x8 aA[4];
        #pragma unroll
        for (int Mt = 0; Mt < 4; ++Mt) {
            int tok = Mt * 16 + lo;
            aA[Mt] = *(const bf16x8*)(xbuf + tok * 512 + (((kk * 4 + hi) ^ (tok & 7)) << 4));
        }
        #pragma unroll
        for (int Mt = 0; Mt < 4; ++Mt)
            #pragma unroll
            for (int nt = 0; nt < 4; ++nt)
                pacc[Mt][nt] = MFMA16(aA[Mt], bB[kk][nt], pacc[Mt][nt]);
    }
    #pragma unroll
    for (int nt = 0; nt < 4; ++nt) {
        int c = wave * 64 + nt * 16 + lo;
        float pb2 = proj_b[c];
        #pragma unroll
        for (int Mt = 0; Mt < 4; ++Mt)
            #pragma unroll
            for (int r = 0; r < 4; ++r) {
                int tok = Mt * 16 + 4 * hi + r;
                int fy = ((wh << 3) + (tok >> 3) + 4) & 63;
                int fx = ((wwi << 3) + (tok & 7) + 4) & 63;
                out[(((b << 6) + fy) * 64 + fx) * 256 + c] = pacc[Mt][nt][r] + pb2;
            }
    }
}

extern "C" void kernel_launch(void* const* d_in, const int* in_sizes, int n_in,
                              void* d_out, int out_size, void* d_ws, size_t ws_size,
                              hipStream_t stream) {
    const float* x       = (const float*)d_in[0];
    const float* qkv_w   = (const float*)d_in[1];
    const float* proj_w  = (const float*)d_in[2];
    const float* proj_b  = (const float*)d_in[3];
    const float* pos_emb = (const float*)d_in[4];

    bf16* wq = (bf16*)d_ws;               // 768*256 bf16
    bf16* wp = wq + QKV_ELEMS;            // 256*256 bf16
    bf16* qkv_ws = wp + PROJ_ELEMS;       // [4096][8][3][2048] bf16

    cvt_weights<<<dim3((QKV_ELEMS + PROJ_ELEMS) / 256), dim3(256), 0, stream>>>(
        qkv_w, proj_w, wq, wp);
    swin_qkv<<<dim3(64 * 64), dim3(256), 0, stream>>>(x, wq, qkv_ws);
    swin_attn_proj<<<dim3(64 * 64), dim3(256), 0, stream>>>(
        qkv_ws, wp, proj_b, pos_emb, (float*)d_out);
}